// Round 1
// baseline (892.338 us; speedup 1.0000x reference)
//
#include <hip/hip_runtime.h>
#include <hip/hip_bf16.h>
#include <math.h>

// Problem constants (reference: BATCH=8, T=2048, N=512)
#define BATCH 8
#define T_LEN 2048
#define NDIM 512
#define M_ROWS (BATCH * T_LEN)   // 16384
#define CHUNK 64                 // scan chunk length
#define NCHUNK (T_LEN / CHUNK)   // 32

// ---------------- GEMM 1: Are/Aim = (gamma*u) @ {B_re, B_im} ----------------
// 64x64 tile, 256 threads, 4x4 per thread, dual accumulators.
#define BM 64
#define BN 64
#define BK 16
#define APAD 4   // pad to 68 floats: keeps float4 alignment (68*4=272=17*16)

__global__ __launch_bounds__(256) void k_gemm_in(
    const float* __restrict__ U, const float* __restrict__ Bre,
    const float* __restrict__ Bim, const float* __restrict__ gamma,
    float* __restrict__ Are, float* __restrict__ Aim)
{
    __shared__ float As[BK][BM + APAD];
    __shared__ float Bsr[BK][BN + APAD];
    __shared__ float Bsi[BK][BN + APAD];

    const int tid = threadIdx.x;
    const int bm = blockIdx.x * BM;
    const int bn = blockIdx.y * BN;
    const int tm = ((tid >> 4) & 15) << 2;  // 0..60
    const int tn = (tid & 15) << 2;         // 0..60

    const int lr = tid >> 4;   // 0..15 (m sub-row for A load)
    const int lc = tid & 15;   // 0..15 (k col for A load)
    const int brow = tid >> 6; // 0..3  (k row for B load)
    const int bcol = tid & 63; // 0..63 (n col for B load)

    float acc_re[4][4] = {};
    float acc_im[4][4] = {};

    for (int k0 = 0; k0 < NDIM; k0 += BK) {
#pragma unroll
        for (int i = 0; i < 4; ++i) {
            int m = bm + lr + i * 16;
            As[lc][lr + i * 16] = U[(size_t)m * NDIM + k0 + lc];
        }
#pragma unroll
        for (int i = 0; i < 4; ++i) {
            int k = k0 + brow + i * 4;
            float g = gamma[k];
            Bsr[brow + i * 4][bcol] = g * Bre[(size_t)k * NDIM + bn + bcol];
            Bsi[brow + i * 4][bcol] = g * Bim[(size_t)k * NDIM + bn + bcol];
        }
        __syncthreads();
#pragma unroll
        for (int k = 0; k < BK; ++k) {
            float a[4], br[4], bi[4];
            *(float4*)a  = *(const float4*)&As[k][tm];
            *(float4*)br = *(const float4*)&Bsr[k][tn];
            *(float4*)bi = *(const float4*)&Bsi[k][tn];
#pragma unroll
            for (int i = 0; i < 4; ++i)
#pragma unroll
                for (int j = 0; j < 4; ++j) {
                    acc_re[i][j] += a[i] * br[j];
                    acc_im[i][j] += a[i] * bi[j];
                }
        }
        __syncthreads();
    }
#pragma unroll
    for (int i = 0; i < 4; ++i) {
        size_t off = (size_t)(bm + tm + i) * NDIM + bn + tn;
        *(float4*)&Are[off] = make_float4(acc_re[i][0], acc_re[i][1], acc_re[i][2], acc_re[i][3]);
        *(float4*)&Aim[off] = make_float4(acc_im[i][0], acc_im[i][1], acc_im[i][2], acc_im[i][3]);
    }
}

// ---------------- Scan pass A: per-chunk local recurrence (in place) --------
// block = (b, chunk), 512 threads (one per n). x_t = lam*x_{t-1} + u_t, x into Are/Aim.
__global__ __launch_bounds__(512) void k_scan_local(
    float* __restrict__ Are, float* __restrict__ Aim,
    const float* __restrict__ nu, const float* __restrict__ theta,
    float* __restrict__ carry_re, float* __restrict__ carry_im)
{
    const int n = threadIdx.x;
    const int blk = blockIdx.x;           // 0..255
    const int b = blk >> 5, c = blk & 31;
    const float ex = __expf(nu[n]);
    const float r = __expf(-ex);
    const float th = theta[n];
    const float lre = r * __cosf(th);
    const float lim = r * __sinf(th);

    size_t base = ((size_t)b * T_LEN + (size_t)c * CHUNK) * NDIM + n;
    float xre = 0.f, xim = 0.f;
    for (int t = 0; t < CHUNK; ++t) {
        size_t idx = base + (size_t)t * NDIM;
        float ure = Are[idx], uim = Aim[idx];
        float nre = lre * xre - lim * xim + ure;
        float nim = lre * xim + lim * xre + uim;
        xre = nre; xim = nim;
        Are[idx] = xre; Aim[idx] = xim;
    }
    size_t ci = ((size_t)b * NCHUNK + c) * NDIM + n;
    carry_re[ci] = xre; carry_im[ci] = xim;
}

// ---------------- Scan pass B: carry scan across chunks ---------------------
// 4096 threads, one per (b,n); sequential over 32 chunks.
__global__ __launch_bounds__(256) void k_scan_carry(
    const float* __restrict__ carry_re, const float* __restrict__ carry_im,
    const float* __restrict__ nu, const float* __restrict__ theta,
    float* __restrict__ pre_re, float* __restrict__ pre_im)
{
    const int tid = blockIdx.x * blockDim.x + threadIdx.x; // 0..4095
    const int b = tid >> 9, n = tid & (NDIM - 1);
    const float ex = __expf(nu[n]);
    const float r64 = __expf(-ex * (float)CHUNK);
    const float th = theta[n] * (float)CHUNK;
    const float a = r64 * __cosf(th);   // lam^CHUNK
    const float bb = r64 * __sinf(th);
    float Xre = 0.f, Xim = 0.f;
    for (int c = 0; c < NCHUNK; ++c) {
        size_t idx = ((size_t)b * NCHUNK + c) * NDIM + n;
        pre_re[idx] = Xre; pre_im[idx] = Xim;   // prefix BEFORE chunk c
        float cre = carry_re[idx], cim = carry_im[idx];
        float nre = a * Xre - bb * Xim + cre;
        float nim = a * Xim + bb * Xre + cim;
        Xre = nre; Xim = nim;
    }
}

// ---------------- Scan pass C: apply prefix (in place) ----------------------
// x[b, c*64+t, n] += lam^{t+1} * P[b,c,n]
__global__ __launch_bounds__(512) void k_scan_apply(
    float* __restrict__ Are, float* __restrict__ Aim,
    const float* __restrict__ nu, const float* __restrict__ theta,
    const float* __restrict__ pre_re, const float* __restrict__ pre_im)
{
    const int n = threadIdx.x;
    const int blk = blockIdx.x;
    const int b = blk >> 5, c = blk & 31;
    if (c == 0) return;  // prefix is zero for first chunk
    size_t pidx = ((size_t)b * NCHUNK + c) * NDIM + n;
    const float Pre = pre_re[pidx], Pim = pre_im[pidx];
    const float ex = __expf(nu[n]);
    const float r = __expf(-ex);
    const float th = theta[n];
    const float lre = r * __cosf(th);
    const float lim = r * __sinf(th);
    float fre = lre, fim = lim;     // lam^{t+1}, t starting at 0
    size_t base = ((size_t)b * T_LEN + (size_t)c * CHUNK) * NDIM + n;
    for (int t = 0; t < CHUNK; ++t) {
        size_t idx = base + (size_t)t * NDIM;
        Are[idx] += fre * Pre - fim * Pim;
        Aim[idx] += fre * Pim + fim * Pre;
        float nfre = fre * lre - fim * lim;
        float nfim = fre * lim + fim * lre;
        fre = nfre; fim = nfim;
    }
}

// ---------------- GEMM 2: y = x_re@C_re - x_im@C_im + D*u -------------------
__global__ __launch_bounds__(256) void k_gemm_out(
    const float* __restrict__ Xre, const float* __restrict__ Xim,
    const float* __restrict__ Cre, const float* __restrict__ Cim,
    const float* __restrict__ D, const float* __restrict__ U,
    float* __restrict__ Y)
{
    __shared__ float Asr[BK][BM + APAD];
    __shared__ float Asi[BK][BM + APAD];
    __shared__ float Bsr[BK][BN + APAD];
    __shared__ float Bsi[BK][BN + APAD];

    const int tid = threadIdx.x;
    const int bm = blockIdx.x * BM;
    const int bn = blockIdx.y * BN;
    const int tm = ((tid >> 4) & 15) << 2;
    const int tn = (tid & 15) << 2;

    const int lr = tid >> 4;
    const int lc = tid & 15;
    const int brow = tid >> 6;
    const int bcol = tid & 63;

    float acc[4][4] = {};

    for (int k0 = 0; k0 < NDIM; k0 += BK) {
#pragma unroll
        for (int i = 0; i < 4; ++i) {
            int m = bm + lr + i * 16;
            Asr[lc][lr + i * 16] = Xre[(size_t)m * NDIM + k0 + lc];
            Asi[lc][lr + i * 16] = Xim[(size_t)m * NDIM + k0 + lc];
        }
#pragma unroll
        for (int i = 0; i < 4; ++i) {
            int k = k0 + brow + i * 4;
            Bsr[brow + i * 4][bcol] = Cre[(size_t)k * NDIM + bn + bcol];
            Bsi[brow + i * 4][bcol] = Cim[(size_t)k * NDIM + bn + bcol];
        }
        __syncthreads();
#pragma unroll
        for (int k = 0; k < BK; ++k) {
            float ar[4], ai[4], br[4], bi[4];
            *(float4*)ar = *(const float4*)&Asr[k][tm];
            *(float4*)ai = *(const float4*)&Asi[k][tm];
            *(float4*)br = *(const float4*)&Bsr[k][tn];
            *(float4*)bi = *(const float4*)&Bsi[k][tn];
#pragma unroll
            for (int i = 0; i < 4; ++i)
#pragma unroll
                for (int j = 0; j < 4; ++j) {
                    acc[i][j] += ar[i] * br[j] - ai[i] * bi[j];
                }
        }
        __syncthreads();
    }

    float d[4];
    *(float4*)d = *(const float4*)&D[bn + tn];
#pragma unroll
    for (int i = 0; i < 4; ++i) {
        size_t off = (size_t)(bm + tm + i) * NDIM + bn + tn;
        float4 uv = *(const float4*)&U[off];
        float4 o;
        o.x = acc[i][0] + d[0] * uv.x;
        o.y = acc[i][1] + d[1] * uv.y;
        o.z = acc[i][2] + d[2] * uv.z;
        o.w = acc[i][3] + d[3] * uv.w;
        *(float4*)&Y[off] = o;
    }
}

extern "C" void kernel_launch(void* const* d_in, const int* in_sizes, int n_in,
                              void* d_out, int out_size, void* d_ws, size_t ws_size,
                              hipStream_t stream)
{
    const float* u     = (const float*)d_in[0];
    const float* C_re  = (const float*)d_in[1];
    const float* C_im  = (const float*)d_in[2];
    const float* B_re  = (const float*)d_in[3];
    const float* B_im  = (const float*)d_in[4];
    const float* D     = (const float*)d_in[5];
    const float* nu    = (const float*)d_in[6];
    const float* theta = (const float*)d_in[7];
    const float* gamma = (const float*)d_in[8];
    float* y = (float*)d_out;

    // Workspace layout (floats): 2x 8388608 (new_u/x re,im in place) + 4x 131072
    float* Are = (float*)d_ws;
    float* Aim = Are + (size_t)M_ROWS * NDIM;
    float* carry_re = Aim + (size_t)M_ROWS * NDIM;
    float* carry_im = carry_re + (size_t)BATCH * NCHUNK * NDIM;
    float* pre_re   = carry_im + (size_t)BATCH * NCHUNK * NDIM;
    float* pre_im   = pre_re + (size_t)BATCH * NCHUNK * NDIM;

    dim3 gemm_grid(M_ROWS / BM, NDIM / BN);  // (256, 8)
    k_gemm_in<<<gemm_grid, 256, 0, stream>>>(u, B_re, B_im, gamma, Are, Aim);
    k_scan_local<<<BATCH * NCHUNK, NDIM, 0, stream>>>(Are, Aim, nu, theta, carry_re, carry_im);
    k_scan_carry<<<(BATCH * NDIM) / 256, 256, 0, stream>>>(carry_re, carry_im, nu, theta, pre_re, pre_im);
    k_scan_apply<<<BATCH * NCHUNK, NDIM, 0, stream>>>(Are, Aim, nu, theta, pre_re, pre_im);
    k_gemm_out<<<gemm_grid, 256, 0, stream>>>(Are, Aim, C_re, C_im, D, u, y);
}

// Round 2
// 313.306 us; speedup vs baseline: 2.8481x; 2.8481x over previous
//
#include <hip/hip_runtime.h>
#include <hip/hip_bf16.h>
#include <math.h>

// Problem constants (reference: BATCH=8, T=2048, N=512)
#define BATCH 8
#define T_LEN 2048
#define NDIM 512
#define M_ROWS (BATCH * T_LEN)   // 16384
#define CHUNK 64                 // scan chunk length
#define NCHUNK (T_LEN / CHUNK)   // 32

#define SK 40                    // LDS k-stride (32 + 8 pad): 80B rows -> 2-way banks (free)

typedef __attribute__((ext_vector_type(8))) short bf16x8;
typedef __attribute__((ext_vector_type(4))) float floatx4;

__device__ __forceinline__ unsigned short f2bf(float f) {
    union { float f; unsigned u; } v; v.f = f;
    unsigned r = v.u + 0x7fff + ((v.u >> 16) & 1);   // RTNE
    return (unsigned short)(r >> 16);
}

// ---------------- GEMM-in (MFMA): [Are|Aim] = (gamma*u) @ [Bre|Bim] ----------
// grid (128, 8): by 0..3 -> Are cols, 4..7 -> Aim cols. 128x128 tile, BK=32.
__global__ __launch_bounds__(256, 2) void k_gemm_in(
    const float* __restrict__ U, const float* __restrict__ Bre,
    const float* __restrict__ Bim, const float* __restrict__ gamma,
    float* __restrict__ Are, float* __restrict__ Aim)
{
    __shared__ unsigned short As[128 * SK];
    __shared__ unsigned short Bs[128 * SK];

    const int tid = threadIdx.x;
    const int w = tid >> 6, l = tid & 63;
    const int bm = blockIdx.x * 128;
    const int by = blockIdx.y;
    const float* __restrict__ Bsrc = (by < 4) ? Bre : Bim;
    float* __restrict__ dst = (by < 4) ? Are : Aim;
    const int bn = (by & 3) * 128;

    const int wm = (w & 1) * 64, wn = (w >> 1) * 64;
    const int lm = l & 15, lq = l >> 4;

    floatx4 acc[4][4];
#pragma unroll
    for (int i = 0; i < 4; ++i)
#pragma unroll
        for (int j = 0; j < 4; ++j) acc[i][j] = (floatx4)0.f;

    for (int k0 = 0; k0 < NDIM; k0 += 32) {
        // stage A: As[row][k] = bf16(gamma[k0+k] * U[bm+row][k0+k])
#pragma unroll
        for (int i = 0; i < 4; ++i) {
            int c = tid + 256 * i;              // 1024 chunks: 128 rows x 8
            int row = c >> 3, kc = (c & 7) * 4;
            float4 uv = *(const float4*)&U[(size_t)(bm + row) * NDIM + k0 + kc];
            float4 gv = *(const float4*)&gamma[k0 + kc];
            ushort4 pk;
            pk.x = f2bf(uv.x * gv.x); pk.y = f2bf(uv.y * gv.y);
            pk.z = f2bf(uv.z * gv.z); pk.w = f2bf(uv.w * gv.w);
            *(ushort4*)&As[row * SK + kc] = pk;
        }
        // stage B (transpose): Bs[n][k] = bf16(Bsrc[k0+k][bn+n])
#pragma unroll
        for (int i = 0; i < 4; ++i) {
            int c = tid + 256 * i;              // 1024 chunks: 32 k x 32 n-quads
            int k = c >> 5, nc = (c & 31) * 4;
            float4 bv = *(const float4*)&Bsrc[(size_t)(k0 + k) * NDIM + bn + nc];
            Bs[(nc + 0) * SK + k] = f2bf(bv.x);
            Bs[(nc + 1) * SK + k] = f2bf(bv.y);
            Bs[(nc + 2) * SK + k] = f2bf(bv.z);
            Bs[(nc + 3) * SK + k] = f2bf(bv.w);
        }
        __syncthreads();

        bf16x8 af[4], bfr[4];
#pragma unroll
        for (int i = 0; i < 4; ++i)
            af[i] = *(const bf16x8*)&As[(wm + i * 16 + lm) * SK + lq * 8];
#pragma unroll
        for (int j = 0; j < 4; ++j)
            bfr[j] = *(const bf16x8*)&Bs[(wn + j * 16 + lm) * SK + lq * 8];
#pragma unroll
        for (int i = 0; i < 4; ++i)
#pragma unroll
            for (int j = 0; j < 4; ++j)
                acc[i][j] = __builtin_amdgcn_mfma_f32_16x16x32_bf16(af[i], bfr[j], acc[i][j], 0, 0, 0);
        __syncthreads();
    }

    // epilogue: C/D layout col=lane&15, row=(lane>>4)*4+r
#pragma unroll
    for (int i = 0; i < 4; ++i)
#pragma unroll
        for (int j = 0; j < 4; ++j) {
            int col = bn + wn + j * 16 + lm;
#pragma unroll
            for (int r = 0; r < 4; ++r) {
                int row = bm + wm + i * 16 + lq * 4 + r;
                dst[(size_t)row * NDIM + col] = acc[i][j][r];
            }
        }
}

// ---------------- Scan pass A: per-chunk local recurrence (in place) --------
__global__ __launch_bounds__(512) void k_scan_local(
    float* __restrict__ Are, float* __restrict__ Aim,
    const float* __restrict__ nu, const float* __restrict__ theta,
    float* __restrict__ carry_re, float* __restrict__ carry_im)
{
    const int n = threadIdx.x;
    const int blk = blockIdx.x;
    const int b = blk >> 5, c = blk & 31;
    const float ex = __expf(nu[n]);
    const float r = __expf(-ex);
    const float th = theta[n];
    const float lre = r * __cosf(th);
    const float lim = r * __sinf(th);

    size_t base = ((size_t)b * T_LEN + (size_t)c * CHUNK) * NDIM + n;
    float xre = 0.f, xim = 0.f;
    for (int t = 0; t < CHUNK; ++t) {
        size_t idx = base + (size_t)t * NDIM;
        float ure = Are[idx], uim = Aim[idx];
        float nre = lre * xre - lim * xim + ure;
        float nim = lre * xim + lim * xre + uim;
        xre = nre; xim = nim;
        Are[idx] = xre; Aim[idx] = xim;
    }
    size_t ci = ((size_t)b * NCHUNK + c) * NDIM + n;
    carry_re[ci] = xre; carry_im[ci] = xim;
}

// ---------------- Scan pass B: carry scan across chunks ---------------------
__global__ __launch_bounds__(256) void k_scan_carry(
    const float* __restrict__ carry_re, const float* __restrict__ carry_im,
    const float* __restrict__ nu, const float* __restrict__ theta,
    float* __restrict__ pre_re, float* __restrict__ pre_im)
{
    const int tid = blockIdx.x * blockDim.x + threadIdx.x;
    const int b = tid >> 9, n = tid & (NDIM - 1);
    const float ex = __expf(nu[n]);
    const float r64 = __expf(-ex * (float)CHUNK);
    const float th = theta[n] * (float)CHUNK;
    const float a = r64 * __cosf(th);
    const float bb = r64 * __sinf(th);
    float Xre = 0.f, Xim = 0.f;
    for (int c = 0; c < NCHUNK; ++c) {
        size_t idx = ((size_t)b * NCHUNK + c) * NDIM + n;
        pre_re[idx] = Xre; pre_im[idx] = Xim;
        float cre = carry_re[idx], cim = carry_im[idx];
        float nre = a * Xre - bb * Xim + cre;
        float nim = a * Xim + bb * Xre + cim;
        Xre = nre; Xim = nim;
    }
}

// ---------------- Scan pass C: apply prefix + convert to bf16 [re|im] -------
// Xbf ALIASES Are (same 32MB region, same row stride 2048B). Per-t barrier
// separates the fp32 reads of row m from the bf16 writes into row m.
__global__ __launch_bounds__(512) void k_scan_apply(
    const float* __restrict__ Are, const float* __restrict__ Aim,
    const float* __restrict__ nu, const float* __restrict__ theta,
    const float* __restrict__ pre_re, const float* __restrict__ pre_im,
    unsigned short* __restrict__ Xbf)
{
    const int n = threadIdx.x;
    const int blk = blockIdx.x;
    const int b = blk >> 5, c = blk & 31;
    size_t pidx = ((size_t)b * NCHUNK + c) * NDIM + n;
    const float Pre = pre_re[pidx], Pim = pre_im[pidx];
    const float ex = __expf(nu[n]);
    const float r = __expf(-ex);
    const float th = theta[n];
    const float lre = r * __cosf(th);
    const float lim = r * __sinf(th);
    float fre = lre, fim = lim;   // lam^{t+1}
    const size_t m0 = (size_t)b * T_LEN + (size_t)c * CHUNK;
    for (int t = 0; t < CHUNK; ++t) {
        size_t m = m0 + t;
        float xre = Are[m * NDIM + n] + fre * Pre - fim * Pim;
        float xim = Aim[m * NDIM + n] + fre * Pim + fim * Pre;
        __syncthreads();            // all reads of row m done before aliased writes
        Xbf[m * 1024 + n] = f2bf(xre);
        Xbf[m * 1024 + 512 + n] = f2bf(xim);
        float nfre = fre * lre - fim * lim;
        float nfim = fre * lim + fim * lre;
        fre = nfre; fim = nfim;
    }
}

// ---------------- GEMM-out (MFMA): y = [Xre|Xim] @ [Cre;-Cim] + D*u ---------
// grid (128, 4). K=1024, 128x128 tile, BK=32.
__global__ __launch_bounds__(256, 2) void k_gemm_out(
    const unsigned short* __restrict__ Xbf,
    const float* __restrict__ Cre, const float* __restrict__ Cim,
    const float* __restrict__ D, const float* __restrict__ U,
    float* __restrict__ Y)
{
    __shared__ unsigned short As[128 * SK];
    __shared__ unsigned short Bs[128 * SK];

    const int tid = threadIdx.x;
    const int w = tid >> 6, l = tid & 63;
    const int bm = blockIdx.x * 128;
    const int bn = blockIdx.y * 128;

    const int wm = (w & 1) * 64, wn = (w >> 1) * 64;
    const int lm = l & 15, lq = l >> 4;

    floatx4 acc[4][4];
#pragma unroll
    for (int i = 0; i < 4; ++i)
#pragma unroll
        for (int j = 0; j < 4; ++j) acc[i][j] = (floatx4)0.f;

    for (int k0 = 0; k0 < 1024; k0 += 32) {
        // stage A: straight bf16 copies from Xbf[m][1024]
#pragma unroll
        for (int i = 0; i < 2; ++i) {
            int c = tid + 256 * i;              // 512 chunks: 128 rows x 4
            int row = c >> 2, kc = (c & 3) * 8;
            uint4 v = *(const uint4*)&Xbf[(size_t)(bm + row) * 1024 + k0 + kc];
            *(uint4*)&As[row * SK + kc] = v;
        }
        // stage B (transpose): Bs[n][k] = bf16(+Cre[k][n] or -Cim[k-512][n])
        const float* __restrict__ Csrc = (k0 < 512) ? Cre : Cim;
        const float sgn = (k0 < 512) ? 1.f : -1.f;
        const int kk0 = k0 & 511;
#pragma unroll
        for (int i = 0; i < 4; ++i) {
            int c = tid + 256 * i;
            int k = c >> 5, nc = (c & 31) * 4;
            float4 bv = *(const float4*)&Csrc[(size_t)(kk0 + k) * NDIM + bn + nc];
            Bs[(nc + 0) * SK + k] = f2bf(sgn * bv.x);
            Bs[(nc + 1) * SK + k] = f2bf(sgn * bv.y);
            Bs[(nc + 2) * SK + k] = f2bf(sgn * bv.z);
            Bs[(nc + 3) * SK + k] = f2bf(sgn * bv.w);
        }
        __syncthreads();

        bf16x8 af[4], bfr[4];
#pragma unroll
        for (int i = 0; i < 4; ++i)
            af[i] = *(const bf16x8*)&As[(wm + i * 16 + lm) * SK + lq * 8];
#pragma unroll
        for (int j = 0; j < 4; ++j)
            bfr[j] = *(const bf16x8*)&Bs[(wn + j * 16 + lm) * SK + lq * 8];
#pragma unroll
        for (int i = 0; i < 4; ++i)
#pragma unroll
            for (int j = 0; j < 4; ++j)
                acc[i][j] = __builtin_amdgcn_mfma_f32_16x16x32_bf16(af[i], bfr[j], acc[i][j], 0, 0, 0);
        __syncthreads();
    }

#pragma unroll
    for (int i = 0; i < 4; ++i)
#pragma unroll
        for (int j = 0; j < 4; ++j) {
            int col = bn + wn + j * 16 + lm;
            float dv = D[col];
#pragma unroll
            for (int r = 0; r < 4; ++r) {
                int row = bm + wm + i * 16 + lq * 4 + r;
                size_t off = (size_t)row * NDIM + col;
                Y[off] = acc[i][j][r] + dv * U[off];
            }
        }
}

extern "C" void kernel_launch(void* const* d_in, const int* in_sizes, int n_in,
                              void* d_out, int out_size, void* d_ws, size_t ws_size,
                              hipStream_t stream)
{
    const float* u     = (const float*)d_in[0];
    const float* C_re  = (const float*)d_in[1];
    const float* C_im  = (const float*)d_in[2];
    const float* B_re  = (const float*)d_in[3];
    const float* B_im  = (const float*)d_in[4];
    const float* D     = (const float*)d_in[5];
    const float* nu    = (const float*)d_in[6];
    const float* theta = (const float*)d_in[7];
    const float* gamma = (const float*)d_in[8];
    float* y = (float*)d_out;

    // Workspace: [Are 32MB (aliased by Xbf bf16 [m][1024])][Aim 32MB][4 smalls 2MB]
    float* Are = (float*)d_ws;
    float* Aim = Are + (size_t)M_ROWS * NDIM;
    float* carry_re = Aim + (size_t)M_ROWS * NDIM;
    float* carry_im = carry_re + (size_t)BATCH * NCHUNK * NDIM;
    float* pre_re   = carry_im + (size_t)BATCH * NCHUNK * NDIM;
    float* pre_im   = pre_re + (size_t)BATCH * NCHUNK * NDIM;
    unsigned short* Xbf = (unsigned short*)d_ws;   // aliases Are

    k_gemm_in<<<dim3(M_ROWS / 128, 8), 256, 0, stream>>>(u, B_re, B_im, gamma, Are, Aim);
    k_scan_local<<<BATCH * NCHUNK, NDIM, 0, stream>>>(Are, Aim, nu, theta, carry_re, carry_im);
    k_scan_carry<<<(BATCH * NDIM) / 256, 256, 0, stream>>>(carry_re, carry_im, nu, theta, pre_re, pre_im);
    k_scan_apply<<<BATCH * NCHUNK, NDIM, 0, stream>>>(Are, Aim, nu, theta, pre_re, pre_im, Xbf);
    k_gemm_out<<<dim3(M_ROWS / 128, 4), 256, 0, stream>>>(Xbf, C_re, C_im, D, u, y);
}

// Round 3
// 182.049 us; speedup vs baseline: 4.9016x; 1.7210x over previous
//
#include <hip/hip_runtime.h>
#include <hip/hip_bf16.h>
#include <math.h>
#include <stdint.h>

// Problem constants (reference: BATCH=8, T=2048, N=512)
#define BATCH 8
#define T_LEN 2048
#define NDIM 512
#define M_ROWS (BATCH * T_LEN)   // 16384
#define CHUNK 32                 // scan chunk length
#define NCHUNK (T_LEN / CHUNK)   // 64

typedef __attribute__((ext_vector_type(8))) short bf16x8;
typedef __attribute__((ext_vector_type(4))) float floatx4;

__device__ __forceinline__ unsigned short f2bf(float f) {
    union { float f; unsigned u; } v; v.f = f;
    unsigned r = v.u + 0x7fff + ((v.u >> 16) & 1);   // RTNE
    return (unsigned short)(r >> 16);
}
__device__ __forceinline__ float bf2f(unsigned short h) {
    union { unsigned u; float f; } v; v.u = ((unsigned)h) << 16;
    return v.f;
}

// async global->LDS, 16 bytes per lane. LDS layout MUST be contiguous in
// lane order (wave-uniform base + lane*16) — hence BK=32, no padding.
__device__ __forceinline__ void gld_lds16(const unsigned short* g, unsigned short* l) {
    __builtin_amdgcn_global_load_lds(
        (const __attribute__((address_space(1))) unsigned int*)(uintptr_t)g,
        (__attribute__((address_space(3))) unsigned int*)(uintptr_t)l,
        16, 0, 0);
}

// ---------------- prep 1: u fp32 -> bf16 ------------------------------------
__global__ __launch_bounds__(256) void k_cvt_u(const float* __restrict__ u,
                                               unsigned short* __restrict__ ubf)
{
    size_t i = ((size_t)blockIdx.x * 256 + threadIdx.x) * 8;
    float4 a = *(const float4*)&u[i];
    float4 b = *(const float4*)&u[i + 4];
    ushort4 p0, p1;
    p0.x = f2bf(a.x); p0.y = f2bf(a.y); p0.z = f2bf(a.z); p0.w = f2bf(a.w);
    p1.x = f2bf(b.x); p1.y = f2bf(b.y); p1.z = f2bf(b.z); p1.w = f2bf(b.w);
    *(ushort4*)&ubf[i] = p0;
    *(ushort4*)&ubf[i + 4] = p1;
}

// ---------------- prep 2: transpose+convert B/C -----------------------------
// z=0: BT[n][k]      = bf16(gamma[k]*B_re[k][n])   (stride 512)
// z=1: BT[512+n][k]  = bf16(gamma[k]*B_im[k][n])
// z=2: CT[n][k]      = bf16( C_re[k][n])           (stride 1024)
// z=3: CT[n][512+k]  = bf16(-C_im[k][n])
__global__ __launch_bounds__(256) void k_prep_T(
    const float* __restrict__ Bre, const float* __restrict__ Bim,
    const float* __restrict__ Cre, const float* __restrict__ Cim,
    const float* __restrict__ gamma,
    unsigned short* __restrict__ BT, unsigned short* __restrict__ CT)
{
    __shared__ unsigned short tile[32][33];
    const int z = blockIdx.z;
    const float* __restrict__ src = (z == 0) ? Bre : (z == 1) ? Bim : (z == 2) ? Cre : Cim;
    const int n0 = blockIdx.x * 32, k0 = blockIdx.y * 32;
    const int tx = threadIdx.x & 31, ty = threadIdx.x >> 5;   // ty 0..7

#pragma unroll
    for (int j = 0; j < 4; ++j) {
        int k = k0 + ty + j * 8;
        float s = (z < 2) ? gamma[k] : (z == 3 ? -1.f : 1.f);
        tile[ty + j * 8][tx] = f2bf(s * src[(size_t)k * NDIM + n0 + tx]);
    }
    __syncthreads();
#pragma unroll
    for (int j = 0; j < 4; ++j) {
        int n = n0 + ty + j * 8;
        unsigned short v = tile[tx][ty + j * 8];
        if (z == 0)      BT[(size_t)n * 512 + k0 + tx] = v;
        else if (z == 1) BT[(size_t)(512 + n) * 512 + k0 + tx] = v;
        else if (z == 2) CT[(size_t)n * 1024 + k0 + tx] = v;
        else             CT[(size_t)n * 1024 + 512 + k0 + tx] = v;
    }
}

// ---------------- GEMM-in: X[16384][1024] = ubf[16384][512] @ BT^T ----------
// m97 structure: 128x128 tile, BK=32, global_load_lds staging, 4 waves 4x4 MFMA.
__global__ __launch_bounds__(256) void k_gemm_in(
    const unsigned short* __restrict__ A,    // [16384][512] bf16
    const unsigned short* __restrict__ BT,   // [1024][512] bf16, n-major
    unsigned short* __restrict__ X)          // [16384][1024] bf16 out
{
    __shared__ unsigned short As[128 * 32];
    __shared__ unsigned short Bs[128 * 32];
    const int tid = threadIdx.x;
    const int w = tid >> 6, l = tid & 63;
    const int bm = blockIdx.x * 128;
    const int bn = blockIdx.y * 128;
    const int wm = (w & 1) * 64, wn = (w >> 1) * 64;
    const int lm = l & 15, lq = l >> 4;
    const int srow = w * 16 + (l >> 2);      // 0..63
    const int scol = (l & 3) * 8;            // 0,8,16,24 shorts

    floatx4 acc[4][4];
#pragma unroll
    for (int i = 0; i < 4; ++i)
#pragma unroll
        for (int j = 0; j < 4; ++j) acc[i][j] = (floatx4)0.f;

    for (int k0 = 0; k0 < 512; k0 += 32) {
        gld_lds16(&A[(size_t)(bm + srow) * 512 + k0 + scol],      &As[srow * 32 + scol]);
        gld_lds16(&A[(size_t)(bm + 64 + srow) * 512 + k0 + scol], &As[(64 + srow) * 32 + scol]);
        gld_lds16(&BT[(size_t)(bn + srow) * 512 + k0 + scol],      &Bs[srow * 32 + scol]);
        gld_lds16(&BT[(size_t)(bn + 64 + srow) * 512 + k0 + scol], &Bs[(64 + srow) * 32 + scol]);
        __syncthreads();

        bf16x8 af[4], bfr[4];
#pragma unroll
        for (int i = 0; i < 4; ++i)
            af[i] = *(const bf16x8*)&As[(wm + i * 16 + lm) * 32 + lq * 8];
#pragma unroll
        for (int j = 0; j < 4; ++j)
            bfr[j] = *(const bf16x8*)&Bs[(wn + j * 16 + lm) * 32 + lq * 8];
#pragma unroll
        for (int i = 0; i < 4; ++i)
#pragma unroll
            for (int j = 0; j < 4; ++j)
                acc[i][j] = __builtin_amdgcn_mfma_f32_16x16x32_bf16(af[i], bfr[j], acc[i][j], 0, 0, 0);
        __syncthreads();
    }

    // C/D layout: col=lane&15, row=(lane>>4)*4+r (verified passing in R2)
#pragma unroll
    for (int i = 0; i < 4; ++i)
#pragma unroll
        for (int j = 0; j < 4; ++j) {
            int col = bn + wn + j * 16 + lm;
#pragma unroll
            for (int r = 0; r < 4; ++r) {
                int row = bm + wm + i * 16 + lq * 4 + r;
                X[(size_t)row * 1024 + col] = f2bf(acc[i][j][r]);
            }
        }
}

// ---------------- Scan pass A: per-chunk carries (read-only on X) -----------
// block=(b,c), 512 threads (one per n, handling the re/im pair).
__global__ __launch_bounds__(512) void k_scan_carries(
    const unsigned short* __restrict__ X,
    const float* __restrict__ nu, const float* __restrict__ theta,
    float* __restrict__ carry)   // [b][c][n] float2 interleaved
{
    const int n = threadIdx.x;
    const int b = blockIdx.x >> 6, c = blockIdx.x & 63;
    const float r = __expf(-__expf(nu[n]));
    const float lre = r * __cosf(theta[n]);
    const float lim = r * __sinf(theta[n]);
    size_t m = (size_t)b * T_LEN + (size_t)c * CHUNK;
    float xre = 0.f, xim = 0.f;
    for (int t = 0; t < CHUNK; ++t, ++m) {
        float ure = bf2f(X[m * 1024 + n]);
        float uim = bf2f(X[m * 1024 + 512 + n]);
        float nre = lre * xre - lim * xim + ure;
        float nim = lre * xim + lim * xre + uim;
        xre = nre; xim = nim;
    }
    size_t ci = ((size_t)b * NCHUNK + c) * NDIM + n;
    *(float2*)&carry[ci * 2] = make_float2(xre, xim);
}

// ---------------- Scan pass B: chain carries across chunks ------------------
__global__ __launch_bounds__(256) void k_scan_chain(
    const float* __restrict__ carry,
    const float* __restrict__ nu, const float* __restrict__ theta,
    float* __restrict__ pre)     // exclusive prefix, float2 interleaved
{
    const int tid = blockIdx.x * blockDim.x + threadIdx.x;  // 0..4095
    const int b = tid >> 9, n = tid & (NDIM - 1);
    const float ex = __expf(nu[n]);
    const float rC = expf(-ex * (float)CHUNK);
    const float th = theta[n] * (float)CHUNK;
    const float a = rC * cosf(th);
    const float bb = rC * sinf(th);
    float Xre = 0.f, Xim = 0.f;
    for (int c = 0; c < NCHUNK; ++c) {
        size_t idx = ((size_t)b * NCHUNK + c) * NDIM + n;
        *(float2*)&pre[idx * 2] = make_float2(Xre, Xim);
        float2 cv = *(const float2*)&carry[idx * 2];
        float nre = a * Xre - bb * Xim + cv.x;
        float nim = a * Xim + bb * Xre + cv.y;
        Xre = nre; Xim = nim;
    }
}

// ---------------- Scan pass C: redo local scan from prefix, in place --------
// Each thread reads & writes only its own slots -> no barriers needed.
__global__ __launch_bounds__(512) void k_scan_apply(
    unsigned short* __restrict__ X,
    const float* __restrict__ nu, const float* __restrict__ theta,
    const float* __restrict__ pre)
{
    const int n = threadIdx.x;
    const int b = blockIdx.x >> 6, c = blockIdx.x & 63;
    size_t pi = ((size_t)b * NCHUNK + c) * NDIM + n;
    float2 P = *(const float2*)&pre[pi * 2];
    const float r = __expf(-__expf(nu[n]));
    const float lre = r * __cosf(theta[n]);
    const float lim = r * __sinf(theta[n]);
    float xre = P.x, xim = P.y;
    size_t m = (size_t)b * T_LEN + (size_t)c * CHUNK;
    for (int t = 0; t < CHUNK; ++t, ++m) {
        float ure = bf2f(X[m * 1024 + n]);
        float uim = bf2f(X[m * 1024 + 512 + n]);
        float nre = lre * xre - lim * xim + ure;
        float nim = lre * xim + lim * xre + uim;
        xre = nre; xim = nim;
        X[m * 1024 + n] = f2bf(xre);
        X[m * 1024 + 512 + n] = f2bf(xim);
    }
}

// ---------------- GEMM-out: Y = X[16384][1024] @ CT^T + D*u -----------------
__global__ __launch_bounds__(256) void k_gemm_out(
    const unsigned short* __restrict__ Xbf,  // [16384][1024] bf16
    const unsigned short* __restrict__ CT,   // [512][1024] bf16, n-major
    const float* __restrict__ D, const float* __restrict__ U,
    float* __restrict__ Y)
{
    __shared__ unsigned short As[128 * 32];
    __shared__ unsigned short Bs[128 * 32];
    const int tid = threadIdx.x;
    const int w = tid >> 6, l = tid & 63;
    const int bm = blockIdx.x * 128;
    const int bn = blockIdx.y * 128;
    const int wm = (w & 1) * 64, wn = (w >> 1) * 64;
    const int lm = l & 15, lq = l >> 4;
    const int srow = w * 16 + (l >> 2);
    const int scol = (l & 3) * 8;

    floatx4 acc[4][4];
#pragma unroll
    for (int i = 0; i < 4; ++i)
#pragma unroll
        for (int j = 0; j < 4; ++j) acc[i][j] = (floatx4)0.f;

    for (int k0 = 0; k0 < 1024; k0 += 32) {
        gld_lds16(&Xbf[(size_t)(bm + srow) * 1024 + k0 + scol],      &As[srow * 32 + scol]);
        gld_lds16(&Xbf[(size_t)(bm + 64 + srow) * 1024 + k0 + scol], &As[(64 + srow) * 32 + scol]);
        gld_lds16(&CT[(size_t)(bn + srow) * 1024 + k0 + scol],       &Bs[srow * 32 + scol]);
        gld_lds16(&CT[(size_t)(bn + 64 + srow) * 1024 + k0 + scol],  &Bs[(64 + srow) * 32 + scol]);
        __syncthreads();

        bf16x8 af[4], bfr[4];
#pragma unroll
        for (int i = 0; i < 4; ++i)
            af[i] = *(const bf16x8*)&As[(wm + i * 16 + lm) * 32 + lq * 8];
#pragma unroll
        for (int j = 0; j < 4; ++j)
            bfr[j] = *(const bf16x8*)&Bs[(wn + j * 16 + lm) * 32 + lq * 8];
#pragma unroll
        for (int i = 0; i < 4; ++i)
#pragma unroll
            for (int j = 0; j < 4; ++j)
                acc[i][j] = __builtin_amdgcn_mfma_f32_16x16x32_bf16(af[i], bfr[j], acc[i][j], 0, 0, 0);
        __syncthreads();
    }

#pragma unroll
    for (int i = 0; i < 4; ++i)
#pragma unroll
        for (int j = 0; j < 4; ++j) {
            int col = bn + wn + j * 16 + lm;
            float dv = D[col];
#pragma unroll
            for (int r = 0; r < 4; ++r) {
                int row = bm + wm + i * 16 + lq * 4 + r;
                size_t off = (size_t)row * NDIM + col;
                Y[off] = acc[i][j][r] + dv * U[off];
            }
        }
}

extern "C" void kernel_launch(void* const* d_in, const int* in_sizes, int n_in,
                              void* d_out, int out_size, void* d_ws, size_t ws_size,
                              hipStream_t stream)
{
    const float* u     = (const float*)d_in[0];
    const float* C_re  = (const float*)d_in[1];
    const float* C_im  = (const float*)d_in[2];
    const float* B_re  = (const float*)d_in[3];
    const float* B_im  = (const float*)d_in[4];
    const float* D     = (const float*)d_in[5];
    const float* nu    = (const float*)d_in[6];
    const float* theta = (const float*)d_in[7];
    const float* gamma = (const float*)d_in[8];
    float* y = (float*)d_out;

    // Workspace (54 MB): X 32MB | ubf 16MB | BT 1MB | CT 1MB | carry 2MB | pre 2MB
    unsigned short* X   = (unsigned short*)d_ws;
    unsigned short* ubf = X + (size_t)M_ROWS * 1024;
    unsigned short* BT  = ubf + (size_t)M_ROWS * 512;
    unsigned short* CT  = BT + (size_t)1024 * 512;
    float* carry = (float*)(CT + (size_t)512 * 1024);
    float* pre   = carry + (size_t)BATCH * NCHUNK * NDIM * 2;

    k_cvt_u<<<(M_ROWS * NDIM) / (256 * 8), 256, 0, stream>>>(u, ubf);
    k_prep_T<<<dim3(16, 16, 4), 256, 0, stream>>>(B_re, B_im, C_re, C_im, gamma, BT, CT);
    k_gemm_in<<<dim3(M_ROWS / 128, 8), 256, 0, stream>>>(ubf, BT, X);
    k_scan_carries<<<BATCH * NCHUNK, NDIM, 0, stream>>>(X, nu, theta, carry);
    k_scan_chain<<<(BATCH * NDIM) / 256, 256, 0, stream>>>(carry, nu, theta, pre);
    k_scan_apply<<<BATCH * NCHUNK, NDIM, 0, stream>>>(X, nu, theta, pre);
    k_gemm_out<<<dim3(M_ROWS / 128, 4), 256, 0, stream>>>(X, CT, D, u, y);
}

// Round 4
// 177.736 us; speedup vs baseline: 5.0206x; 1.0243x over previous
//
#include <hip/hip_runtime.h>
#include <hip/hip_bf16.h>
#include <math.h>
#include <stdint.h>

// Problem constants (reference: BATCH=8, T=2048, N=512)
#define BATCH 8
#define T_LEN 2048
#define NDIM 512
#define M_ROWS (BATCH * T_LEN)   // 16384
#define CHUNK 32                 // scan chunk length
#define NCHUNK (T_LEN / CHUNK)   // 64

typedef __attribute__((ext_vector_type(8))) short bf16x8;
typedef __attribute__((ext_vector_type(4))) float floatx4;

__device__ __forceinline__ unsigned short f2bf(float f) {
    union { float f; unsigned u; } v; v.f = f;
    unsigned r = v.u + 0x7fff + ((v.u >> 16) & 1);   // RTNE
    return (unsigned short)(r >> 16);
}
__device__ __forceinline__ float bf2f(unsigned short h) {
    union { unsigned u; float f; } v; v.u = ((unsigned)h) << 16;
    return v.f;
}
__device__ __forceinline__ float bf2f_lo(unsigned u) {
    union { unsigned u; float f; } v; v.u = u << 16; return v.f;
}
__device__ __forceinline__ float bf2f_hi(unsigned u) {
    union { unsigned u; float f; } v; v.u = u & 0xffff0000u; return v.f;
}

// async global->LDS, 16 bytes per lane. LDS layout MUST be contiguous in
// lane order (wave-uniform base + lane*16) — hence BK=32, no padding.
__device__ __forceinline__ void gld_lds16(const unsigned short* g, unsigned short* l) {
    __builtin_amdgcn_global_load_lds(
        (const __attribute__((address_space(1))) unsigned int*)(uintptr_t)g,
        (__attribute__((address_space(3))) unsigned int*)(uintptr_t)l,
        16, 0, 0);
}

// ---------------- prep (merged): u->bf16  +  transpose/convert B,C ----------
// blocks [0,4096): cvt_u flat; blocks [4096,5120): transpose tiles.
__global__ __launch_bounds__(256) void k_prep(
    const float* __restrict__ u,
    const float* __restrict__ Bre, const float* __restrict__ Bim,
    const float* __restrict__ Cre, const float* __restrict__ Cim,
    const float* __restrict__ gamma,
    unsigned short* __restrict__ ubf,
    unsigned short* __restrict__ BT, unsigned short* __restrict__ CT)
{
    __shared__ unsigned short tile[32][33];
    const int blk = blockIdx.x;
    if (blk < 4096) {
        size_t i = ((size_t)blk * 256 + threadIdx.x) * 8;
        float4 a = *(const float4*)&u[i];
        float4 b = *(const float4*)&u[i + 4];
        ushort4 p0, p1;
        p0.x = f2bf(a.x); p0.y = f2bf(a.y); p0.z = f2bf(a.z); p0.w = f2bf(a.w);
        p1.x = f2bf(b.x); p1.y = f2bf(b.y); p1.z = f2bf(b.z); p1.w = f2bf(b.w);
        *(ushort4*)&ubf[i] = p0;
        *(ushort4*)&ubf[i + 4] = p1;
        return;
    }
    const int p = blk - 4096;
    const int z = p >> 8;                    // 0..3
    const int rem = p & 255;
    const int n0 = (rem & 15) * 32, k0 = (rem >> 4) * 32;
    const float* __restrict__ src = (z == 0) ? Bre : (z == 1) ? Bim : (z == 2) ? Cre : Cim;
    const int tx = threadIdx.x & 31, ty = threadIdx.x >> 5;   // ty 0..7

#pragma unroll
    for (int j = 0; j < 4; ++j) {
        int k = k0 + ty + j * 8;
        float s = (z < 2) ? gamma[k] : (z == 3 ? -1.f : 1.f);
        tile[ty + j * 8][tx] = f2bf(s * src[(size_t)k * NDIM + n0 + tx]);
    }
    __syncthreads();
#pragma unroll
    for (int j = 0; j < 4; ++j) {
        int n = n0 + ty + j * 8;
        unsigned short v = tile[tx][ty + j * 8];
        if (z == 0)      BT[(size_t)n * 512 + k0 + tx] = v;
        else if (z == 1) BT[(size_t)(512 + n) * 512 + k0 + tx] = v;
        else if (z == 2) CT[(size_t)n * 1024 + k0 + tx] = v;
        else             CT[(size_t)n * 1024 + 512 + k0 + tx] = v;
    }
}

// ---------------- GEMM-in: X[16384][1024] = ubf[16384][512] @ BT^T ----------
__global__ __launch_bounds__(256) void k_gemm_in(
    const unsigned short* __restrict__ A,    // [16384][512] bf16
    const unsigned short* __restrict__ BT,   // [1024][512] bf16, n-major
    unsigned short* __restrict__ X)          // [16384][1024] bf16 out
{
    __shared__ unsigned short As[128 * 32];
    __shared__ unsigned short Bs[128 * 32];
    const int tid = threadIdx.x;
    const int w = tid >> 6, l = tid & 63;
    const int bm = blockIdx.x * 128;
    const int bn = blockIdx.y * 128;
    const int wm = (w & 1) * 64, wn = (w >> 1) * 64;
    const int lm = l & 15, lq = l >> 4;
    const int srow = w * 16 + (l >> 2);
    const int scol = (l & 3) * 8;

    floatx4 acc[4][4];
#pragma unroll
    for (int i = 0; i < 4; ++i)
#pragma unroll
        for (int j = 0; j < 4; ++j) acc[i][j] = (floatx4)0.f;

    for (int k0 = 0; k0 < 512; k0 += 32) {
        gld_lds16(&A[(size_t)(bm + srow) * 512 + k0 + scol],      &As[srow * 32 + scol]);
        gld_lds16(&A[(size_t)(bm + 64 + srow) * 512 + k0 + scol], &As[(64 + srow) * 32 + scol]);
        gld_lds16(&BT[(size_t)(bn + srow) * 512 + k0 + scol],      &Bs[srow * 32 + scol]);
        gld_lds16(&BT[(size_t)(bn + 64 + srow) * 512 + k0 + scol], &Bs[(64 + srow) * 32 + scol]);
        __syncthreads();

        bf16x8 af[4], bfr[4];
#pragma unroll
        for (int i = 0; i < 4; ++i)
            af[i] = *(const bf16x8*)&As[(wm + i * 16 + lm) * 32 + lq * 8];
#pragma unroll
        for (int j = 0; j < 4; ++j)
            bfr[j] = *(const bf16x8*)&Bs[(wn + j * 16 + lm) * 32 + lq * 8];
#pragma unroll
        for (int i = 0; i < 4; ++i)
#pragma unroll
            for (int j = 0; j < 4; ++j)
                acc[i][j] = __builtin_amdgcn_mfma_f32_16x16x32_bf16(af[i], bfr[j], acc[i][j], 0, 0, 0);
        __syncthreads();
    }

#pragma unroll
    for (int i = 0; i < 4; ++i)
#pragma unroll
        for (int j = 0; j < 4; ++j) {
            int col = bn + wn + j * 16 + lm;
#pragma unroll
            for (int r = 0; r < 4; ++r) {
                int row = bm + wm + i * 16 + lq * 4 + r;
                X[(size_t)row * 1024 + col] = f2bf(acc[i][j][r]);
            }
        }
}

// ---------------- Scan pass A: per-chunk carries (2 channels/thread) --------
__global__ __launch_bounds__(256) void k_scan_carries(
    const unsigned short* __restrict__ X,
    const float* __restrict__ nu, const float* __restrict__ theta,
    float* __restrict__ carry)   // [b][c][n] float2 interleaved
{
    const int t2 = threadIdx.x;                 // handles n = 2*t2, 2*t2+1
    const int n0 = 2 * t2;
    const int b = blockIdx.x >> 6, c = blockIdx.x & 63;
    float r0 = __expf(-__expf(nu[n0]));
    float r1 = __expf(-__expf(nu[n0 + 1]));
    float lre0 = r0 * __cosf(theta[n0]),     lim0 = r0 * __sinf(theta[n0]);
    float lre1 = r1 * __cosf(theta[n0 + 1]), lim1 = r1 * __sinf(theta[n0 + 1]);
    size_t m = (size_t)b * T_LEN + (size_t)c * CHUNK;
    float xre0 = 0.f, xim0 = 0.f, xre1 = 0.f, xim1 = 0.f;
#pragma unroll 8
    for (int t = 0; t < CHUNK; ++t, ++m) {
        unsigned re = *(const unsigned*)&X[m * 1024 + n0];
        unsigned im = *(const unsigned*)&X[m * 1024 + 512 + n0];
        float u0 = bf2f_lo(re), u1 = bf2f_hi(re);
        float v0 = bf2f_lo(im), v1 = bf2f_hi(im);
        float a0 = lre0 * xre0 - lim0 * xim0 + u0;
        float b0 = lre0 * xim0 + lim0 * xre0 + v0;
        float a1 = lre1 * xre1 - lim1 * xim1 + u1;
        float b1 = lre1 * xim1 + lim1 * xre1 + v1;
        xre0 = a0; xim0 = b0; xre1 = a1; xim1 = b1;
    }
    size_t ci = ((size_t)b * NCHUNK + c) * NDIM + n0;
    *(float4*)&carry[ci * 2] = make_float4(xre0, xim0, xre1, xim1);
}

// ---------------- Scan pass B: chain carries across chunks ------------------
__global__ __launch_bounds__(256) void k_scan_chain(
    const float* __restrict__ carry,
    const float* __restrict__ nu, const float* __restrict__ theta,
    float* __restrict__ pre)     // exclusive prefix, float2 interleaved
{
    const int tid = blockIdx.x * blockDim.x + threadIdx.x;  // 0..4095
    const int b = tid >> 9, n = tid & (NDIM - 1);
    const float ex = __expf(nu[n]);
    const float rC = expf(-ex * (float)CHUNK);
    const float th = theta[n] * (float)CHUNK;
    const float a = rC * cosf(th);
    const float bb = rC * sinf(th);
    float Xre = 0.f, Xim = 0.f;
    for (int c = 0; c < NCHUNK; ++c) {
        size_t idx = ((size_t)b * NCHUNK + c) * NDIM + n;
        *(float2*)&pre[idx * 2] = make_float2(Xre, Xim);
        float2 cv = *(const float2*)&carry[idx * 2];
        float nre = a * Xre - bb * Xim + cv.x;
        float nim = a * Xim + bb * Xre + cv.y;
        Xre = nre; Xim = nim;
    }
}

// ---------------- Scan pass C: redo local scan from prefix, in place --------
__global__ __launch_bounds__(256) void k_scan_apply(
    unsigned short* __restrict__ X,
    const float* __restrict__ nu, const float* __restrict__ theta,
    const float* __restrict__ pre)
{
    const int t2 = threadIdx.x;
    const int n0 = 2 * t2;
    const int b = blockIdx.x >> 6, c = blockIdx.x & 63;
    size_t pi = ((size_t)b * NCHUNK + c) * NDIM + n0;
    float4 P = *(const float4*)&pre[pi * 2];    // (re0, im0, re1, im1)
    float r0 = __expf(-__expf(nu[n0]));
    float r1 = __expf(-__expf(nu[n0 + 1]));
    float lre0 = r0 * __cosf(theta[n0]),     lim0 = r0 * __sinf(theta[n0]);
    float lre1 = r1 * __cosf(theta[n0 + 1]), lim1 = r1 * __sinf(theta[n0 + 1]);
    float xre0 = P.x, xim0 = P.y, xre1 = P.z, xim1 = P.w;
    size_t m = (size_t)b * T_LEN + (size_t)c * CHUNK;
#pragma unroll 8
    for (int t = 0; t < CHUNK; ++t, ++m) {
        unsigned re = *(const unsigned*)&X[m * 1024 + n0];
        unsigned im = *(const unsigned*)&X[m * 1024 + 512 + n0];
        float u0 = bf2f_lo(re), u1 = bf2f_hi(re);
        float v0 = bf2f_lo(im), v1 = bf2f_hi(im);
        float a0 = lre0 * xre0 - lim0 * xim0 + u0;
        float b0 = lre0 * xim0 + lim0 * xre0 + v0;
        float a1 = lre1 * xre1 - lim1 * xim1 + u1;
        float b1 = lre1 * xim1 + lim1 * xre1 + v1;
        xre0 = a0; xim0 = b0; xre1 = a1; xim1 = b1;
        unsigned pr = (unsigned)f2bf(xre0) | ((unsigned)f2bf(xre1) << 16);
        unsigned pim = (unsigned)f2bf(xim0) | ((unsigned)f2bf(xim1) << 16);
        *(unsigned*)&X[m * 1024 + n0] = pr;
        *(unsigned*)&X[m * 1024 + 512 + n0] = pim;
    }
}

// ---------------- GEMM-out: Y = X[16384][1024] @ CT^T + D*u -----------------
__global__ __launch_bounds__(256) void k_gemm_out(
    const unsigned short* __restrict__ Xbf,  // [16384][1024] bf16
    const unsigned short* __restrict__ CT,   // [512][1024] bf16, n-major
    const float* __restrict__ D,
    const unsigned short* __restrict__ Ubf,  // [16384][512] bf16 (for D*u)
    float* __restrict__ Y)
{
    __shared__ unsigned short As[128 * 32];
    __shared__ unsigned short Bs[128 * 32];
    const int tid = threadIdx.x;
    const int w = tid >> 6, l = tid & 63;
    const int bm = blockIdx.x * 128;
    const int bn = blockIdx.y * 128;
    const int wm = (w & 1) * 64, wn = (w >> 1) * 64;
    const int lm = l & 15, lq = l >> 4;
    const int srow = w * 16 + (l >> 2);
    const int scol = (l & 3) * 8;

    floatx4 acc[4][4];
#pragma unroll
    for (int i = 0; i < 4; ++i)
#pragma unroll
        for (int j = 0; j < 4; ++j) acc[i][j] = (floatx4)0.f;

    for (int k0 = 0; k0 < 1024; k0 += 32) {
        gld_lds16(&Xbf[(size_t)(bm + srow) * 1024 + k0 + scol],      &As[srow * 32 + scol]);
        gld_lds16(&Xbf[(size_t)(bm + 64 + srow) * 1024 + k0 + scol], &As[(64 + srow) * 32 + scol]);
        gld_lds16(&CT[(size_t)(bn + srow) * 1024 + k0 + scol],       &Bs[srow * 32 + scol]);
        gld_lds16(&CT[(size_t)(bn + 64 + srow) * 1024 + k0 + scol],  &Bs[(64 + srow) * 32 + scol]);
        __syncthreads();

        bf16x8 af[4], bfr[4];
#pragma unroll
        for (int i = 0; i < 4; ++i)
            af[i] = *(const bf16x8*)&As[(wm + i * 16 + lm) * 32 + lq * 8];
#pragma unroll
        for (int j = 0; j < 4; ++j)
            bfr[j] = *(const bf16x8*)&Bs[(wn + j * 16 + lm) * 32 + lq * 8];
#pragma unroll
        for (int i = 0; i < 4; ++i)
#pragma unroll
            for (int j = 0; j < 4; ++j)
                acc[i][j] = __builtin_amdgcn_mfma_f32_16x16x32_bf16(af[i], bfr[j], acc[i][j], 0, 0, 0);
        __syncthreads();
    }

#pragma unroll
    for (int i = 0; i < 4; ++i)
#pragma unroll
        for (int j = 0; j < 4; ++j) {
            int col = bn + wn + j * 16 + lm;
            float dv = D[col];
#pragma unroll
            for (int r = 0; r < 4; ++r) {
                int row = bm + wm + i * 16 + lq * 4 + r;
                size_t off = (size_t)row * NDIM + col;
                Y[off] = acc[i][j][r] + dv * bf2f(Ubf[off]);
            }
        }
}

extern "C" void kernel_launch(void* const* d_in, const int* in_sizes, int n_in,
                              void* d_out, int out_size, void* d_ws, size_t ws_size,
                              hipStream_t stream)
{
    const float* u     = (const float*)d_in[0];
    const float* C_re  = (const float*)d_in[1];
    const float* C_im  = (const float*)d_in[2];
    const float* B_re  = (const float*)d_in[3];
    const float* B_im  = (const float*)d_in[4];
    const float* D     = (const float*)d_in[5];
    const float* nu    = (const float*)d_in[6];
    const float* theta = (const float*)d_in[7];
    const float* gamma = (const float*)d_in[8];
    float* y = (float*)d_out;

    // Workspace (54 MB): X 32MB | ubf 16MB | BT 1MB | CT 1MB | carry 2MB | pre 2MB
    unsigned short* X   = (unsigned short*)d_ws;
    unsigned short* ubf = X + (size_t)M_ROWS * 1024;
    unsigned short* BT  = ubf + (size_t)M_ROWS * 512;
    unsigned short* CT  = BT + (size_t)1024 * 512;
    float* carry = (float*)(CT + (size_t)512 * 1024);
    float* pre   = carry + (size_t)BATCH * NCHUNK * NDIM * 2;

    k_prep<<<4096 + 1024, 256, 0, stream>>>(u, B_re, B_im, C_re, C_im, gamma, ubf, BT, CT);
    k_gemm_in<<<dim3(M_ROWS / 128, 8), 256, 0, stream>>>(ubf, BT, X);
    k_scan_carries<<<BATCH * NCHUNK, 256, 0, stream>>>(X, nu, theta, carry);
    k_scan_chain<<<(BATCH * NDIM) / 256, 256, 0, stream>>>(carry, nu, theta, pre);
    k_scan_apply<<<BATCH * NCHUNK, 256, 0, stream>>>(X, nu, theta, pre);
    k_gemm_out<<<dim3(M_ROWS / 128, 4), 256, 0, stream>>>(X, CT, D, ubf, y);
}